// Round 17
// baseline (298.084 us; speedup 1.0000x reference)
//
#include <hip/hip_runtime.h>
#include <hip/hip_bf16.h>
#include <hip/hip_fp16.h>
#include <math.h>

#define N0c 120000
#define N1c 20000
#define N2c 6000
#define N3c 1600
#define E1c 480000
#define E2c 144000
#define E3c 38400

#define HB1 256   // hist/scatter blocks for conv1 (1250 bins of dst>>4)
#define HB2 480   // hist/scatter blocks for conv2 cube sort
#define HB3 160   // hist/scatter blocks for conv3 cube sort
#define WCVB 125  // one block per knot-slice k for W2/W3 transpose-convert
#define WC1B 32   // W1 fp16 convert blocks (64*128/256)
#define SS0B  469 // (120000+255)/256
#define OFFB  345 // ceil(1378*64/256) offset-scan blocks in off_all
#define DECB  79  // (20000+255)/256 xm1-decode blocks in off_all

typedef __attribute__((ext_vector_type(8))) short short8;
typedef __attribute__((ext_vector_type(8))) _Float16 half8;
typedef __attribute__((ext_vector_type(4))) float f32x4;

__device__ __forceinline__ float eluf(float x) {
    return x > 0.0f ? x : expm1f(x);
}

__device__ __forceinline__ unsigned f2sort(float f) {
    unsigned u = __float_as_uint(f);
    return (u & 0x80000000u) ? ~u : (u | 0x80000000u);
}
__device__ __forceinline__ float sort2f(unsigned u) {
    unsigned bits = (u & 0x80000000u) ? (u & 0x7FFFFFFFu) : ~u;
    return __uint_as_float(bits);
}
__device__ __forceinline__ unsigned short f2bf(float v) {
    unsigned u = __float_as_uint(v);
    unsigned r = (u + 0x7FFFu + ((u >> 16) & 1u)) >> 16;   // RNE
    return (unsigned short)r;
}
__device__ __forceinline__ unsigned short f2h(float v) {
    return __half_as_ushort(__float2half(v));
}
__device__ __forceinline__ float h2f(unsigned short u) {
    return __half2float(__ushort_as_half(u));
}

// ---- STAGE A: all feature-independent prep, one kernel, blockIdx ranges ----
// W2t/W3t LANE-LINEAR layout (validated +15us win): per (tap k, frag f,
// 16-col block cb) a contiguous 1KB block indexed [mc][q][8 halves].
__global__ __launch_bounds__(256) void hist_all(
    const int* __restrict__ edge1, const int* __restrict__ edge2,
    const int* __restrict__ edge3,
    const float* __restrict__ pseudo2, const float* __restrict__ pseudo3,
    const float* __restrict__ W2, const float* __restrict__ W3,
    const float* __restrict__ W1,
    const float* __restrict__ x0, const int* __restrict__ cluster0,
    int* __restrict__ blockCnt1, int* __restrict__ binTot1,
    int* __restrict__ blockCnt2, int* __restrict__ binTot2, int* __restrict__ cntD2,
    int* __restrict__ blockCnt3, int* __restrict__ binTot3, int* __restrict__ cntD3,
    unsigned short* __restrict__ W2t, unsigned short* __restrict__ W3t,
    unsigned short* __restrict__ W1t,
    unsigned* __restrict__ xm1)
{
    __shared__ float smf[64 * 129];   // 33KB; aliased as int* for hists
    int* h = (int*)smf;
    int b = blockIdx.x, t = threadIdx.x;
    if (b < HB1) {
        for (int i = t; i < 1250; i += 256) h[i] = 0;
        __syncthreads();
        for (int e = b * 256 + t; e < E1c; e += HB1 * 256)
            atomicAdd(&h[edge1[E1c + e] >> 4], 1);
        __syncthreads();
        for (int i = t; i < 1250; i += 256) {
            int v = h[i];
            blockCnt1[i * HB1 + b] = v;
            if (v) atomicAdd(&binTot1[i], v);
        }
    } else if (b < HB1 + HB2 + HB3) {
        bool is2 = b < HB1 + HB2;
        int rb = is2 ? (b - HB1) : (b - HB1 - HB2);
        int nblk = is2 ? HB2 : HB3;
        int E = is2 ? E2c : E3c;
        const int* edge = is2 ? edge2 : edge3;
        const float* pseudo = is2 ? pseudo2 : pseudo3;
        int* blockCnt = is2 ? blockCnt2 : blockCnt3;
        int* binTot = is2 ? binTot2 : binTot3;
        int* dstCnt = is2 ? cntD2 : cntD3;
        int nb = is2 ? HB2 : HB3;
        if (t < 64) h[t] = 0;
        __syncthreads();
        for (int e = rb * 256 + t; e < E; e += nblk * 256) {
            int c = 0, mul = 1;
            #pragma unroll
            for (int d = 0; d < 3; d++) {
                float p = pseudo[e * 3 + d] * 4.0f;
                float l = fminf(fmaxf(floorf(p), 0.0f), 3.0f);
                c += (int)l * mul;
                mul <<= 2;
            }
            atomicAdd(&h[c], 1);
            atomicAdd(&dstCnt[edge[E + e]], 1);
        }
        __syncthreads();
        if (t < 64) {
            int v = h[t];
            blockCnt[t * nb + rb] = v;
            if (v) atomicAdd(&binTot[t], v);
        }
    } else if (b < HB1 + HB2 + HB3 + WCVB) {
        int k = b - (HB1 + HB2 + HB3);
        for (int idx = t; idx < 4096; idx += 256) {
            int n = idx & 63, ic = idx >> 6;
            smf[ic * 65 + n] = W2[((size_t)k * 64 + ic) * 64 + n];
        }
        __syncthreads();
        for (int idx = t; idx < 4096; idx += 256) {
            int ic = idx & 63, n = idx >> 6;
            int f = ic >> 5, q = (ic >> 3) & 3, hh = ic & 7;
            int cb = n >> 4, mc = n & 15;
            W2t[((size_t)((k * 2 + f) * 4 + cb)) * 512 + mc * 32 + q * 8 + hh]
                = f2bf(smf[ic * 65 + n]);
        }
    } else if (b < HB1 + HB2 + HB3 + 2 * WCVB) {
        int k = b - (HB1 + HB2 + HB3 + WCVB);
        for (int idx = t; idx < 8192; idx += 256) {
            int n = idx & 127, ic = idx >> 7;
            smf[ic * 129 + n] = W3[((size_t)k * 64 + ic) * 128 + n];
        }
        __syncthreads();
        for (int idx = t; idx < 8192; idx += 256) {
            int ic = idx & 63, n = idx >> 6;   // n < 128
            int f = ic >> 5, q = (ic >> 3) & 3, hh = ic & 7;
            int cb = n >> 4, mc = n & 15;
            W3t[((size_t)((k * 2 + f) * 8 + cb)) * 512 + mc * 32 + q * 8 + hh]
                = f2bf(smf[ic * 129 + n]);
        }
    } else if (b < HB1 + HB2 + HB3 + 2 * WCVB + WC1B) {
        int idx = (b - (HB1 + HB2 + HB3 + 2 * WCVB)) * 256 + t;   // < 8192
        int n = idx >> 7, k = idx & 127;
        W1t[idx] = (k < 125) ? f2h(W1[k * 64 + n]) : (unsigned short)0;
    } else {
        int idx = (b - (HB1 + HB2 + HB3 + 2 * WCVB + WC1B)) * 256 + t;
        if (idx < N0c)
            atomicMax(&xm1[cluster0[idx]], f2sort(x0[idx]));
    }
}

// ---- STAGE B1: scans (conv1 1250 bins, conv2/3 bins + dsts) + chunk maps ----
__global__ __launch_bounds__(256) void plan_tot(
    const int* __restrict__ binTot1, int* __restrict__ start1,
    const int* __restrict__ binTot2, int* __restrict__ binCnt2,
    int* __restrict__ binStart2, int* __restrict__ blkPrefix2,
    int* __restrict__ chunkBin2, int* __restrict__ chunkOff2,
    const int* __restrict__ binTot3, int* __restrict__ binCnt3,
    int* __restrict__ binStart3, int* __restrict__ blkPrefix3,
    int* __restrict__ chunkBin3, int* __restrict__ chunkOff3,
    const int* __restrict__ cntD2, int* __restrict__ dstStart2,
    const int* __restrict__ cntD3, int* __restrict__ dstStart3)
{
    __shared__ int ps[256];
    __shared__ int ps64[64];
    int t = threadIdx.x;

    // conv1: thread t owns bins [5t, 5t+5)
    {
        int loc[5];
        int s = 0;
        #pragma unroll
        for (int i = 0; i < 5; i++) {
            int bin = t * 5 + i;
            int v = (bin < 1250) ? binTot1[bin] : 0;
            loc[i] = v;
            s += v;
        }
        ps[t] = s;
        __syncthreads();
        for (int ofs = 1; ofs < 256; ofs <<= 1) {
            int add = (t >= ofs) ? ps[t - ofs] : 0;
            __syncthreads();
            ps[t] += add;
            __syncthreads();
        }
        int run = (t == 0) ? 0 : ps[t - 1];
        #pragma unroll
        for (int i = 0; i < 5; i++) {
            int bin = t * 5 + i;
            if (bin < 1250) {
                start1[bin] = run;
                run += loc[i];
            }
        }
        if (t == 255) start1[1250] = run;
    }
    __syncthreads();

    // conv2: totals, starts, chunk map (chunk = 64 edges)
    if (t < 64) {
        int v = binTot2[t];
        binCnt2[t] = v;
        ps64[t] = v;
    }
    __syncthreads();
    if (t == 0) {
        int s2 = 0, p = 0;
        for (int c = 0; c < 64; c++) {
            int v = ps64[c];
            binStart2[c] = s2;
            blkPrefix2[c] = p;
            s2 += v;
            p += (v + 63) >> 6;
        }
        binStart2[64] = s2;
        blkPrefix2[64] = p;
    }
    __syncthreads();
    if (t < 64) {
        int nch = (binCnt2[t] + 63) >> 6;
        int base = blkPrefix2[t];
        for (int j = 0; j < nch; j++) {
            chunkBin2[base + j] = t;
            chunkOff2[base + j] = j;
        }
    }
    __syncthreads();

    // conv3
    if (t < 64) {
        int v = binTot3[t];
        binCnt3[t] = v;
        ps64[t] = v;
    }
    __syncthreads();
    if (t == 0) {
        int s3 = 0, p = 0;
        for (int c = 0; c < 64; c++) {
            int v = ps64[c];
            binStart3[c] = s3;
            blkPrefix3[c] = p;
            s3 += v;
            p += (v + 63) >> 6;
        }
        binStart3[64] = s3;
        blkPrefix3[64] = p;
    }
    __syncthreads();
    if (t < 64) {
        int nch = (binCnt3[t] + 63) >> 6;
        int base = blkPrefix3[t];
        for (int j = 0; j < nch; j++) {
            chunkBin3[base + j] = t;
            chunkOff3[base + j] = j;
        }
    }
    __syncthreads();

    // conv2 dst scan: 6000 bins, 24 per thread
    {
        int locd[24];
        int sd = 0;
        #pragma unroll
        for (int i = 0; i < 24; i++) {
            int bin = t * 24 + i;
            int vv = (bin < N2c) ? cntD2[bin] : 0;
            locd[i] = vv;
            sd += vv;
        }
        ps[t] = sd;
        __syncthreads();
        for (int ofs = 1; ofs < 256; ofs <<= 1) {
            int add = (t >= ofs) ? ps[t - ofs] : 0;
            __syncthreads();
            ps[t] += add;
            __syncthreads();
        }
        int rund = (t == 0) ? 0 : ps[t - 1];
        #pragma unroll
        for (int i = 0; i < 24; i++) {
            int bin = t * 24 + i;
            if (bin < N2c) { dstStart2[bin] = rund; rund += locd[i]; }
        }
        if (t == 255) dstStart2[N2c] = ps[255];
    }
    __syncthreads();

    // conv3 dst scan: 1600 bins, 7 per thread
    {
        int locd[7];
        int sd = 0;
        #pragma unroll
        for (int i = 0; i < 7; i++) {
            int bin = t * 7 + i;
            int vv = (bin < N3c) ? cntD3[bin] : 0;
            locd[i] = vv;
            sd += vv;
        }
        ps[t] = sd;
        __syncthreads();
        for (int ofs = 1; ofs < 256; ofs <<= 1) {
            int add = (t >= ofs) ? ps[t - ofs] : 0;
            __syncthreads();
            ps[t] += add;
            __syncthreads();
        }
        int rund = (t == 0) ? 0 : ps[t - 1];
        #pragma unroll
        for (int i = 0; i < 7; i++) {
            int bin = t * 7 + i;
            if (bin < N3c) { dstStart3[bin] = rund; rund += locd[i]; }
        }
        if (t == 255) dstStart3[N3c] = ps[255];
    }
}

// ---- STAGE B2: per-(bin,block) offsets (one wave per bin-row, shfl scan)
// + xm1 sortable->fp32 decode (runs before scatter reads fp32 x).
__global__ __launch_bounds__(256) void off_all(
    const int* __restrict__ blockCnt1, const int* __restrict__ start1,
    int* __restrict__ blockOff1,
    const int* __restrict__ blockCnt2, const int* __restrict__ binStart2,
    int* __restrict__ blockOff2,
    const int* __restrict__ blockCnt3, const int* __restrict__ binStart3,
    int* __restrict__ blockOff3,
    unsigned* __restrict__ xm1)
{
    if (blockIdx.x >= OFFB) {
        int idx = (blockIdx.x - OFFB) * 256 + threadIdx.x;
        if (idx < N1c) {
            float f = sort2f(xm1[idx]);
            unsigned bb = __float_as_uint(f);
            if ((bb & 0x7F800000u) == 0x7F800000u) f = 0.0f;
            ((float*)xm1)[idx] = f;
        }
        return;
    }
    int wid = (blockIdx.x * 256 + threadIdx.x) >> 6;
    int lane = threadIdx.x & 63;
    if (wid >= 1250 + 64 + 64) return;
    const int* c;
    int* o;
    int run, width;
    if (wid < 1250) {
        c = blockCnt1 + (size_t)wid * HB1;
        o = blockOff1 + (size_t)wid * HB1;
        run = start1[wid];
        width = HB1;
    } else if (wid < 1250 + 64) {
        int bin = wid - 1250;
        c = blockCnt2 + (size_t)bin * HB2;
        o = blockOff2 + (size_t)bin * HB2;
        run = binStart2[bin];
        width = HB2;
    } else {
        int bin = wid - 1314;
        c = blockCnt3 + (size_t)bin * HB3;
        o = blockOff3 + (size_t)bin * HB3;
        run = binStart3[bin];
        width = HB3;
    }
    for (int base = 0; base < width; base += 64) {
        int b = base + lane;
        int v = (b < width) ? c[b] : 0;
        int inc = v;
        #pragma unroll
        for (int ofs = 1; ofs < 64; ofs <<= 1) {
            int u = __shfl_up(inc, ofs);
            if (lane >= ofs) inc += u;
        }
        if (b < width) o[b] = run + inc - v;
        run += __shfl(inc, 63);
    }
}

// ---- STAGE C: scatter EDGE RECORDS ----
// conv1: 1250-bin placement; xv INLINED into the record:
//        rec1 = { f0:fp16<<16 | kbase<<4 | ln, xv:f32, f1:f32, f2:f32 }.
// conv2/3: cube-bin placement + dst-sorted posList (counting sort).
__global__ __launch_bounds__(256) void scatter_all(
    const int* __restrict__ edge1, const float* __restrict__ pseudo1,
    const int* __restrict__ edge2, const float* __restrict__ pseudo2,
    const int* __restrict__ edge3, const float* __restrict__ pseudo3,
    const int* __restrict__ blockOff1,
    const int* __restrict__ blockOff2, const int* __restrict__ blockOff3,
    int4* __restrict__ rec1, int4* __restrict__ rec2, int4* __restrict__ rec3,
    const float* __restrict__ x1,
    const int* __restrict__ dstStart2, const int* __restrict__ dstStart3,
    int* __restrict__ curD2, int* __restrict__ curD3,
    int* __restrict__ posList2, int* __restrict__ posList3)
{
    __shared__ int cur[1250];
    int b = blockIdx.x, t = threadIdx.x;
    if (b < HB1) {
        for (int i = t; i < 1250; i += 256) cur[i] = blockOff1[(size_t)i * HB1 + b];
        __syncthreads();
        for (int e = b * 256 + t; e < E1c; e += HB1 * 256) {
            int src = edge1[e], dst = edge1[E1c + e];
            float f[3];
            int kbase = 0, mul5 = 1;
            #pragma unroll
            for (int d = 0; d < 3; d++) {
                float pp = pseudo1[e * 3 + d] * 4.0f;
                float l = fminf(fmaxf(floorf(pp), 0.0f), 3.0f);
                f[d] = pp - l;
                kbase += (int)l * mul5;
                mul5 *= 5;
            }
            float xv = x1[src];
            int p = atomicAdd(&cur[dst >> 4], 1);
            rec1[p] = make_int4(((int)f2h(f[0]) << 16) | (kbase << 4) | (dst & 15),
                                __float_as_int(xv), __float_as_int(f[1]),
                                __float_as_int(f[2]));
        }
    } else {
        bool is2 = b < HB1 + HB2;
        int rb = is2 ? (b - HB1) : (b - HB1 - HB2);
        int nblk = is2 ? HB2 : HB3;
        int E = is2 ? E2c : E3c;
        const int* edge = is2 ? edge2 : edge3;
        const float* pseudo = is2 ? pseudo2 : pseudo3;
        const int* blockOff = is2 ? blockOff2 : blockOff3;
        int4* rec = is2 ? rec2 : rec3;
        const int* dstStart = is2 ? dstStart2 : dstStart3;
        int* curD = is2 ? curD2 : curD3;
        int* posList = is2 ? posList2 : posList3;
        int nb = is2 ? HB2 : HB3;
        if (t < 64) cur[t] = blockOff[(size_t)t * nb + rb];
        __syncthreads();
        for (int e = rb * 256 + t; e < E; e += nblk * 256) {
            int src = edge[e], dst = edge[E + e];
            float f[3];
            int c = 0, mul = 1;
            #pragma unroll
            for (int d = 0; d < 3; d++) {
                float pp = pseudo[e * 3 + d] * 4.0f;
                float l = fminf(fmaxf(floorf(pp), 0.0f), 3.0f);
                f[d] = pp - l;
                c += (int)l * mul;
                mul <<= 2;
            }
            int p = atomicAdd(&cur[c], 1);
            rec[p] = make_int4(src | (dst << 16),
                               __float_as_int(f[0]), __float_as_int(f[1]),
                               __float_as_int(f[2]));
            int qd = dstStart[dst] + atomicAdd(&curD[dst], 1);
            posList[qd] = p;
        }
    }
}

// ---- conv1 (C_in=1): per-16-node block, LDS knot accumulation; epilogue is
// a 16x64x128 fp16 MFMA GEMM (T16 @ W1t). Pools into xm2 via atomicMax.
__global__ __launch_bounds__(256) void conv1_block(
    const int4* __restrict__ rec, const float* __restrict__ x,
    const int* __restrict__ start,
    const unsigned short* __restrict__ W1t,   // [64][128] fp16 k-contig
    const float* __restrict__ root,
    const float* __restrict__ bias, const int* __restrict__ cl,
    unsigned* __restrict__ xmOut) {
    __shared__ float T[16][128];
    __shared__ unsigned short T16[16][136];   // pad 136: 16B-aligned rows, 2-way banks
    __shared__ int degL[16];
    int b = blockIdx.x;
    int t = threadIdx.x;
    for (int j = t; j < 2048; j += 256) ((float*)T)[j] = 0.0f;
    if (t < 16) degL[t] = 0;
    __syncthreads();
    int s0 = start[b], s1 = start[b + 1];
    for (int i = s0 + t; i < s1; i += 256) {
        int4 r = rec[i];
        int ln = r.x & 15;
        int kbase = (r.x >> 4) & 127;
        float f0 = h2f((unsigned short)((unsigned)r.x >> 16));
        float xv = __int_as_float(r.y);
        float f1 = __int_as_float(r.z);
        float f2 = __int_as_float(r.w);
        #pragma unroll
        for (int s = 0; s < 8; s++) {
            int b0 = s & 1, b1 = (s >> 1) & 1, b2 = (s >> 2) & 1;
            float w0 = b0 ? f0 : 1.0f - f0;
            float w1 = b1 ? f1 : 1.0f - f1;
            float w2 = b2 ? f2 : 1.0f - f2;
            int k = kbase + b0 + 5 * b1 + 25 * b2;
            atomicAdd(&T[ln][k], xv * w0 * w1 * w2);
        }
        atomicAdd(&degL[ln], 1);
    }
    __syncthreads();
    // T fp32 -> T16 fp16 (k 125..127 are zero from init)
    for (int j = t; j < 2048; j += 256) {
        int node = j >> 7, k = j & 127;
        T16[node][k] = f2h(T[node][k]);
    }
    __syncthreads();
    int w = t >> 6, lane = t & 63;
    int q = lane >> 4, mcol = lane & 15;
    const unsigned short* ar = &T16[mcol][0];
    half8 a0 = *(const half8*)(ar + q * 8);
    half8 a1 = *(const half8*)(ar + 32 + q * 8);
    half8 a2 = *(const half8*)(ar + 64 + q * 8);
    half8 a3 = *(const half8*)(ar + 96 + q * 8);
    int ch = w * 16 + mcol;
    const unsigned short* br = W1t + (size_t)ch * 128;
    half8 b0 = *(const half8*)(br + q * 8);
    half8 b1 = *(const half8*)(br + 32 + q * 8);
    half8 b2 = *(const half8*)(br + 64 + q * 8);
    half8 b3 = *(const half8*)(br + 96 + q * 8);
    f32x4 c = (f32x4){0.0f, 0.0f, 0.0f, 0.0f};
    c = __builtin_amdgcn_mfma_f32_16x16x32_f16(a0, b0, c, 0, 0, 0);
    c = __builtin_amdgcn_mfma_f32_16x16x32_f16(a1, b1, c, 0, 0, 0);
    c = __builtin_amdgcn_mfma_f32_16x16x32_f16(a2, b2, c, 0, 0, 0);
    c = __builtin_amdgcn_mfma_f32_16x16x32_f16(a3, b3, c, 0, 0, 0);
    int v0 = b << 4;
    float rt_ = root[ch], bi = bias[ch];
    #pragma unroll
    for (int r = 0; r < 4; r++) {
        int node = q * 4 + r;
        int v = v0 + node;
        float d = fmaxf((float)degL[node], 1.0f);
        float val = eluf(c[r] / d + x[v] * rt_ + bi);
        atomicMax(&xmOut[((size_t)cl[v] << 6) + ch], f2sort(val));
    }
}

// decode pooled sortable-uint buffer -> fp32 (in place) + bf16 copy
__global__ void decode_cvt(unsigned* __restrict__ buf,
                           unsigned short* __restrict__ xb, int total) {
    int idx = blockIdx.x * blockDim.x + threadIdx.x;
    if (idx >= total) return;
    float f = sort2f(buf[idx]);
    unsigned b = __float_as_uint(f);
    if ((b & 0x7F800000u) == 0x7F800000u) f = 0.0f;
    ((float*)buf)[idx] = f;
    xb[idx] = f2bf(f);
}

// Binned spline-conv via bf16 MFMA. Wave = 64 edges x 32 cols (2 N-tiles),
// gridDim.y = COUT/32 column slices. B-fragments lane-linear (coalesced 1KB).
// msg is SLICE-MAJOR: COUT/32 planes of [eTot][32] halves. The C-tile is
// transposed through LDS (CtS, pad-40 rows -> 2-way banks) so each rt-group
// stores one DENSE 1KB b128 instruction (old path: 32 stores at 25% line
// density -> TA-serialized, same disease as the fixed B-loads).
template<int COUT>
__global__ __launch_bounds__(256) void spline_mfma(
    const int4* __restrict__ recs,
    const unsigned short* __restrict__ Wt,
    const unsigned short* __restrict__ xb,
    const int* __restrict__ binStart,
    const int* __restrict__ binCnt,
    const int* __restrict__ blkPrefix,
    const int* __restrict__ chunkBin,
    const int* __restrict__ chunkOff,
    unsigned short* __restrict__ msg, int eTot)
{
    __shared__ float basisS[4][8][64];
    __shared__ int srcS[4][64];
    __shared__ unsigned short CtS[4][16][40];   // 5KB; pad-40 rows

    int w = threadIdx.x >> 6, lane = threadIdx.x & 63;
    int c = blockIdx.x * 4 + w;
    if (c >= blkPrefix[64]) return;
    int bin = chunkBin[c];
    int chunk = chunkOff[c];
    int cnt = binCnt[bin];

    {
        int pos = chunk * 64 + lane;
        bool act = pos < cnt;
        int4 r = act ? recs[binStart[bin] + pos] : make_int4(0, 0, 0, 0);
        srcS[w][lane] = r.x & 0xFFFF;
        float f0 = __int_as_float(r.y);
        float f1 = __int_as_float(r.z);
        float f2 = __int_as_float(r.w);
        #pragma unroll
        for (int s = 0; s < 8; s++) {
            float w0 = (s & 1) ? f0 : 1.0f - f0;
            float w1 = (s & 2) ? f1 : 1.0f - f1;
            float w2 = (s & 4) ? f2 : 1.0f - f2;
            basisS[w][s][lane] = act ? (w0 * w1 * w2) : 0.0f;
        }
    }
    __builtin_amdgcn_wave_barrier();
    __threadfence_block();

    int lo0 = bin & 3, lo1 = (bin >> 2) & 3, lo2 = bin >> 4;
    int kbase = lo0 + 5 * lo1 + 25 * lo2;
    int colOff = blockIdx.y << 5;   // 32-col slice
    int q = lane >> 4;        // quad
    int mcol = lane & 15;
    int cb0 = colOff >> 4;
    int lof = (mcol << 5) + (q << 3);   // lane offset in halves within 512-half block

    short8 afr[4][2];
    #pragma unroll
    for (int rt = 0; rt < 4; rt++) {
        int src = srcS[w][rt * 16 + mcol];
        const unsigned short* xr = xb + ((size_t)src << 6) + q * 8;
        afr[rt][0] = *(const short8*)(xr);
        afr[rt][1] = *(const short8*)(xr + 32);
    }

    f32x4 acc[4][2];
    #pragma unroll
    for (int rt = 0; rt < 4; rt++)
        #pragma unroll
        for (int nt = 0; nt < 2; nt++)
            acc[rt][nt] = (f32x4){0.0f, 0.0f, 0.0f, 0.0f};
    const f32x4 zero4 = {0.0f, 0.0f, 0.0f, 0.0f};

    // tap-k: k(s) = kbase + (s&1) + 5*((s>>1)&1) + 25*(s>>2)
    short8 bcur[2][2];
    {
        #pragma unroll
        for (int nt = 0; nt < 2; nt++) {
            bcur[nt][0] = *(const short8*)(Wt + ((size_t)((kbase * 2 + 0) * (COUT >> 4) + cb0 + nt)) * 512 + lof);
            bcur[nt][1] = *(const short8*)(Wt + ((size_t)((kbase * 2 + 1) * (COUT >> 4) + cb0 + nt)) * 512 + lof);
        }
    }
    #pragma unroll 1
    for (int s = 0; s < 8; s++) {
        short8 bnx[2][2];
        if (s < 7) {
            int sn = s + 1;
            int kn = kbase + (sn & 1) + 5 * ((sn >> 1) & 1) + 25 * (sn >> 2);
            #pragma unroll
            for (int nt = 0; nt < 2; nt++) {
                bnx[nt][0] = *(const short8*)(Wt + ((size_t)((kn * 2 + 0) * (COUT >> 4) + cb0 + nt)) * 512 + lof);
                bnx[nt][1] = *(const short8*)(Wt + ((size_t)((kn * 2 + 1) * (COUT >> 4) + cb0 + nt)) * 512 + lof);
            }
        }
        #pragma unroll
        for (int rt = 0; rt < 4; rt++) {
            f32x4 ct[2];
            #pragma unroll
            for (int nt = 0; nt < 2; nt++) {
                ct[nt] = __builtin_amdgcn_mfma_f32_16x16x32_bf16(afr[rt][0], bcur[nt][0], zero4, 0, 0, 0);
                ct[nt] = __builtin_amdgcn_mfma_f32_16x16x32_bf16(afr[rt][1], bcur[nt][1], ct[nt], 0, 0, 0);
            }
            #pragma unroll
            for (int r = 0; r < 4; r++) {
                float bs = basisS[w][s][rt * 16 + q * 4 + r];
                #pragma unroll
                for (int nt = 0; nt < 2; nt++)
                    acc[rt][nt][r] = fmaf(bs, ct[nt][r], acc[rt][nt][r]);
            }
        }
        if (s < 7) {
            #pragma unroll
            for (int nt = 0; nt < 2; nt++) {
                bcur[nt][0] = bnx[nt][0];
                bcur[nt][1] = bnx[nt][1];
            }
        }
    }

    // Epilogue: LDS-transpose per rt-group, then one dense 1KB store.
    int base = binStart[bin] + chunk * 64;
    unsigned short* msgP = msg + (size_t)blockIdx.y * eTot * 32;
    int lrow = lane >> 2, seg = lane & 3;
    #pragma unroll
    for (int rt = 0; rt < 4; rt++) {
        #pragma unroll
        for (int r = 0; r < 4; r++) {
            int row = q * 4 + r;
            #pragma unroll
            for (int nt = 0; nt < 2; nt++)
                CtS[w][row][nt * 16 + mcol] = f2h(acc[rt][nt][r]);
        }
        __builtin_amdgcn_wave_barrier();
        __threadfence_block();
        int grow = rt * 16 + lrow;
        if (chunk * 64 + grow < cnt) {
            short8 vv = *(const short8*)&CtS[w][lrow][seg * 8];
            *(short8*)(msgP + (((size_t)(base + grow)) << 5) + seg * 8) = vv;
        }
        __builtin_amdgcn_wave_barrier();
        __threadfence_block();
    }
}

// gather-aggregate + node update (mean + root matmul + bias + elu) + pool,
// COUT=64. One wave per node; msg is 2 planes of [E2][32] halves.
__global__ __launch_bounds__(256) void agg_update64(
    const unsigned short* __restrict__ msg, const int* __restrict__ posList,
    const int* __restrict__ dstStart,
    const float* __restrict__ xm, const float* __restrict__ root,
    const float* __restrict__ bias, const int* __restrict__ cl,
    unsigned* __restrict__ xmOut, int nNodes) {
    __shared__ float xsh[4][64];
    int w = threadIdx.x >> 6, lane = threadIdx.x & 63;
    int v = blockIdx.x * 4 + w;
    if (v >= nNodes) return;
    xsh[w][lane] = xm[((size_t)v << 6) + lane];
    const unsigned short* mpl = msg + ((size_t)(lane >> 5)) * ((size_t)E2c * 32);
    int cl32 = lane & 31;
    int s0 = dstStart[v], s1 = dstStart[v + 1];
    float a0 = 0.0f, a1 = 0.0f, a2 = 0.0f, a3 = 0.0f;
    int i = s0;
    for (; i + 4 <= s1; i += 4) {
        int p0 = posList[i], p1 = posList[i + 1];
        int p2 = posList[i + 2], p3 = posList[i + 3];
        a0 += h2f(mpl[((size_t)p0 << 5) + cl32]);
        a1 += h2f(mpl[((size_t)p1 << 5) + cl32]);
        a2 += h2f(mpl[((size_t)p2 << 5) + cl32]);
        a3 += h2f(mpl[((size_t)p3 << 5) + cl32]);
    }
    for (; i < s1; i++)
        a0 += h2f(mpl[((size_t)posList[i] << 5) + cl32]);
    float a = (a0 + a1 + a2 + a3) / fmaxf((float)(s1 - s0), 1.0f);
    float r = 0.0f;
    #pragma unroll 8
    for (int j = 0; j < 64; j++)
        r = fmaf(xsh[w][j], root[(j << 6) + lane], r);
    float val = eluf(a + r + bias[lane]);
    atomicMax(&xmOut[((size_t)cl[v] << 6) + lane], f2sort(val));
}

// gather-aggregate + node update + pool, COUT=128 (2 channels/lane);
// msg is 4 planes of [E3][32] halves: ch=lane -> planes 0/1, ch=64+lane -> 2/3.
__global__ __launch_bounds__(256) void agg_update128(
    const unsigned short* __restrict__ msg, const int* __restrict__ posList,
    const int* __restrict__ dstStart,
    const float* __restrict__ xm, const float* __restrict__ root,
    const float* __restrict__ bias, const int* __restrict__ cl,
    unsigned* __restrict__ xmOut, int nNodes) {
    __shared__ float xsh[4][64];
    int w = threadIdx.x >> 6, lane = threadIdx.x & 63;
    int v = blockIdx.x * 4 + w;
    if (v >= nNodes) return;
    xsh[w][lane] = xm[((size_t)v << 6) + lane];
    const unsigned short* mA = msg + ((size_t)(lane >> 5)) * ((size_t)E3c * 32);
    const unsigned short* mB = msg + ((size_t)(2 + (lane >> 5))) * ((size_t)E3c * 32);
    int cl32 = lane & 31;
    int s0 = dstStart[v], s1 = dstStart[v + 1];
    float c0a = 0.0f, c0b = 0.0f, c1a = 0.0f, c1b = 0.0f;
    int i = s0;
    for (; i + 2 <= s1; i += 2) {
        int p0 = posList[i], p1 = posList[i + 1];
        c0a += h2f(mA[((size_t)p0 << 5) + cl32]); c0b += h2f(mB[((size_t)p0 << 5) + cl32]);
        c1a += h2f(mA[((size_t)p1 << 5) + cl32]); c1b += h2f(mB[((size_t)p1 << 5) + cl32]);
    }
    for (; i < s1; i++) {
        int p0 = posList[i];
        c0a += h2f(mA[((size_t)p0 << 5) + cl32]); c0b += h2f(mB[((size_t)p0 << 5) + cl32]);
    }
    float dinv = 1.0f / fmaxf((float)(s1 - s0), 1.0f);
    float aa0 = (c0a + c1a) * dinv;
    float aa1 = (c0b + c1b) * dinv;
    float r0 = 0.0f, r1 = 0.0f;
    #pragma unroll 8
    for (int j = 0; j < 64; j++) {
        float xi = xsh[w][j];
        r0 = fmaf(xi, root[(j << 7) + lane], r0);
        r1 = fmaf(xi, root[(j << 7) + 64 + lane], r1);
    }
    unsigned* orow = xmOut + ((size_t)cl[v] << 7);
    atomicMax(&orow[lane], f2sort(eluf(aa0 + r0 + bias[lane])));
    atomicMax(&orow[64 + lane], f2sort(eluf(aa1 + r1 + bias[lane + 64])));
}

// fc1 k-split: grid (64 rows, 8 k-slices). Inline sortable-uint decode of xm4.
__global__ __launch_bounds__(256) void fc1_split(
    const unsigned* __restrict__ xin, const float* __restrict__ w1,
    float* __restrict__ h) {
    __shared__ float xsh[128];
    int row = blockIdx.x, ks = blockIdx.y;
    int o = threadIdx.x;
    if (o < 128) {
        float f = sort2f(xin[row * 1024 + ks * 128 + o]);
        unsigned bb = __float_as_uint(f);
        if ((bb & 0x7F800000u) == 0x7F800000u) f = 0.0f;
        xsh[o] = f;
    }
    __syncthreads();
    float acc = 0.0f;
    const float* wp = w1 + (size_t)ks * 128 * 256 + o;
    #pragma unroll 8
    for (int i = 0; i < 128; i++)
        acc = fmaf(xsh[i], wp[i * 256], acc);
    atomicAdd(&h[row * 256 + o], acc);
}

// fc2 + log_softmax: elu(h+b1) @ w2 + b2. One block (64 thr) per row.
__global__ __launch_bounds__(64) void fc2_k(
    const float* __restrict__ h, const float* __restrict__ b1,
    const float* __restrict__ w2, const float* __restrict__ b2,
    float* __restrict__ out) {
    __shared__ float hs[256];
    __shared__ float lg[10];
    int row = blockIdx.x;
    int t = threadIdx.x;
    for (int i = t; i < 256; i += 64) hs[i] = eluf(h[row * 256 + i] + b1[i]);
    __syncthreads();
    if (t < 10) {
        float a = b2[t];
        for (int i = 0; i < 256; i++) a = fmaf(hs[i], w2[i * 10 + t], a);
        lg[t] = a;
    }
    __syncthreads();
    if (t < 10) {
        float m = -1e30f;
        #pragma unroll
        for (int j = 0; j < 10; j++) m = fmaxf(m, lg[j]);
        float sum = 0.0f;
        #pragma unroll
        for (int j = 0; j < 10; j++) sum += expf(lg[j] - m);
        out[row * 10 + t] = lg[t] - m - logf(sum);
    }
}

extern "C" void kernel_launch(void* const* d_in, const int* in_sizes, int n_in,
                              void* d_out, int out_size, void* d_ws, size_t ws_size,
                              hipStream_t stream) {
    const float* x0      = (const float*)d_in[0];
    const int*   cluster0= (const int*)d_in[1];
    const int*   edge1   = (const int*)d_in[2];
    const float* pseudo1 = (const float*)d_in[3];
    const float* W1      = (const float*)d_in[4];
    const float* root1   = (const float*)d_in[5];
    const float* b1      = (const float*)d_in[6];
    const int*   cluster1= (const int*)d_in[7];
    const int*   edge2   = (const int*)d_in[8];
    const float* pseudo2 = (const float*)d_in[9];
    const float* W2      = (const float*)d_in[10];
    const float* root2   = (const float*)d_in[11];
    const float* b2      = (const float*)d_in[12];
    const int*   cluster2= (const int*)d_in[13];
    const int*   edge3   = (const int*)d_in[14];
    const float* pseudo3 = (const float*)d_in[15];
    const float* W3      = (const float*)d_in[16];
    const float* root3   = (const float*)d_in[17];
    const float* b3      = (const float*)d_in[18];
    const int*   cluster3= (const int*)d_in[19];
    const float* fc1_w   = (const float*)d_in[20];
    const float* fc1_b   = (const float*)d_in[21];
    const float* fc2_w   = (const float*)d_in[22];
    const float* fc2_b   = (const float*)d_in[23];
    float* out = (float*)d_out;

    float* ws = (float*)d_ws;
    size_t off = 0;
    // ---- zeroed region ----
    float* xm1  = ws + off; off += 20480;
    float* xm2  = ws + off; off += (size_t)N2c * 64;
    float* xm3  = ws + off; off += (size_t)N3c * 64;
    float* xm4  = ws + off; off += 512 * 128;
    float* h1   = ws + off; off += 64 * 256;
    int* cntD2   = (int*)(ws + off); off += 6016;
    int* cntD3   = (int*)(ws + off); off += 1664;
    int* curD2   = (int*)(ws + off); off += 6016;
    int* curD3   = (int*)(ws + off); off += 1664;
    int* binTot1 = (int*)(ws + off); off += 1280;
    int* binTot2 = (int*)(ws + off); off += 64;
    int* binTot3 = (int*)(ws + off); off += 64;
    size_t zeroFloats = off;
    // ---- non-zeroed region (fully written before read every launch) ----
    int4* rec1 = (int4*)(ws + off); off += (size_t)E1c * 4;
    int4* rec2 = (int4*)(ws + off); off += (size_t)E2c * 4;
    int4* rec3 = (int4*)(ws + off); off += (size_t)E3c * 4;
    unsigned short* W2t = (unsigned short*)(ws + off); off += 256000;
    unsigned short* W3t = (unsigned short*)(ws + off); off += 512000;
    unsigned short* W1t = (unsigned short*)(ws + off); off += 4096;
    unsigned short* xb2 = (unsigned short*)(ws + off); off += 192000;
    unsigned short* xb3 = (unsigned short*)(ws + off); off += 51200;
    int* start1    = (int*)(ws + off); off += 1280;
    int* blockCnt1 = (int*)(ws + off); off += (size_t)HB1 * 1250;
    int* blockOff1 = (int*)(ws + off); off += (size_t)HB1 * 1250;
    int* blockCnt2 = (int*)(ws + off); off += (size_t)HB2 * 64;
    int* blockOff2 = (int*)(ws + off); off += (size_t)HB2 * 64;
    int* blockCnt3 = (int*)(ws + off); off += (size_t)HB3 * 64;
    int* blockOff3 = (int*)(ws + off); off += (size_t)HB3 * 64;
    int* binCnt2   = (int*)(ws + off); off += 64;
    int* binStart2 = (int*)(ws + off); off += 80;
    int* blkPrefix2= (int*)(ws + off); off += 80;
    int* chunkBin2 = (int*)(ws + off); off += 2560;
    int* chunkOff2 = (int*)(ws + off); off += 2560;
    int* binCnt3   = (int*)(ws + off); off += 64;
    int* binStart3 = (int*)(ws + off); off += 80;
    int* blkPrefix3= (int*)(ws + off); off += 80;
    int* chunkBin3 = (int*)(ws + off); off += 768;
    int* chunkOff3 = (int*)(ws + off); off += 768;
    int* dstStart2 = (int*)(ws + off); off += 6016;
    int* dstStart3 = (int*)(ws + off); off += 1664;
    int* posList2  = (int*)(ws + off); off += E2c;
    int* posList3  = (int*)(ws + off); off += E3c;
    // slice-major fp16 message buffer: conv2 2 planes [E2][32],
    // conv3 4 planes [E3][32] (smaller); shared allocation
    unsigned short* msg = (unsigned short*)(ws + off); off += (size_t)E2c * 32;

    hipMemsetAsync(d_ws, 0, zeroFloats * sizeof(float), stream);

    // A: hists + W transpose-cvt (lane-linear W2t/W3t, W1 fp16) + pool0
    hist_all<<<HB1 + HB2 + HB3 + 2 * WCVB + WC1B + SS0B, 256, 0, stream>>>(
        edge1, edge2, edge3, pseudo2, pseudo3, W2, W3, W1, x0, cluster0,
        blockCnt1, binTot1, blockCnt2, binTot2, cntD2,
        blockCnt3, binTot3, cntD3, W2t, W3t, W1t, (unsigned*)xm1);

    // B1: scans (conv1 bins, conv2/3 bins + dsts) + chunk maps
    plan_tot<<<1, 256, 0, stream>>>(
        binTot1, start1,
        binTot2, binCnt2, binStart2, blkPrefix2, chunkBin2, chunkOff2,
        binTot3, binCnt3, binStart3, blkPrefix3, chunkBin3, chunkOff3,
        cntD2, dstStart2, cntD3, dstStart3);

    // B2: per-(bin,block) offsets (wave scan) + xm1 decode
    off_all<<<OFFB + DECB, 256, 0, stream>>>(
        blockCnt1, start1, blockOff1,
        blockCnt2, binStart2, blockOff2,
        blockCnt3, binStart3, blockOff3, (unsigned*)xm1);

    // C: scatter edge records (conv1 with inlined xv) + posLists
    scatter_all<<<HB1 + HB2 + HB3, 256, 0, stream>>>(
        edge1, pseudo1, edge2, pseudo2, edge3, pseudo3,
        blockOff1, blockOff2, blockOff3, rec1, rec2, rec3, xm1,
        dstStart2, dstStart3, curD2, curD3, posList2, posList3);

    // conv1 (1->64): LDS knot accumulation + fp16 MFMA epilogue + pool
    conv1_block<<<1250, 256, 0, stream>>>(rec1, xm1, start1, W1t, root1, b1,
                                          cluster1, (unsigned*)xm2);
    decode_cvt<<<(N2c * 64) / 256, 256, 0, stream>>>((unsigned*)xm2, xb2, N2c * 64);

    // conv2 (64->64): coalesced-B MFMA + dense plane stores, agg + pool
    spline_mfma<64><<<dim3((E2c / 64 + 64 + 3) / 4, 2), 256, 0, stream>>>(
        rec2, W2t, xb2, binStart2, binCnt2, blkPrefix2, chunkBin2, chunkOff2,
        msg, E2c);
    agg_update64<<<(N2c + 3) / 4, 256, 0, stream>>>(msg, posList2, dstStart2,
                                                    xm2, root2, b2, cluster2,
                                                    (unsigned*)xm3, N2c);
    decode_cvt<<<(N3c * 64) / 256, 256, 0, stream>>>((unsigned*)xm3, xb3, N3c * 64);

    // conv3 (64->128): coalesced-B MFMA + dense plane stores, agg + pool
    spline_mfma<128><<<dim3((E3c / 64 + 64 + 3) / 4, 4), 256, 0, stream>>>(
        rec3, W3t, xb3, binStart3, binCnt3, blkPrefix3, chunkBin3, chunkOff3,
        msg, E3c);
    agg_update128<<<(N3c + 3) / 4, 256, 0, stream>>>(msg, posList3, dstStart3,
                                                     xm3, root3, b3, cluster3,
                                                     (unsigned*)xm4, N3c);

    // FC head: k-split fc1 (inline xm4 decode) + fused fc2/log_softmax
    fc1_split<<<dim3(64, 8), 256, 0, stream>>>((unsigned*)xm4, fc1_w, h1);
    fc2_k<<<64, 64, 0, stream>>>(h1, fc1_b, fc2_w, fc2_b, out);
}

// Round 18
// 294.725 us; speedup vs baseline: 1.0114x; 1.0114x over previous
//
#include <hip/hip_runtime.h>
#include <hip/hip_bf16.h>
#include <hip/hip_fp16.h>
#include <math.h>

#define N0c 120000
#define N1c 20000
#define N2c 6000
#define N3c 1600
#define E1c 480000
#define E2c 144000
#define E3c 38400

#define HB1 256   // hist/scatter blocks for conv1 (1250 bins of dst>>4)
#define HB2 480   // hist/scatter blocks for conv2 cube sort
#define HB3 160   // hist/scatter blocks for conv3 cube sort
#define WCVB 125  // one block per knot-slice k for W2/W3 transpose-convert
#define WC1B 32   // W1 fp16 convert blocks (64*128/256)
#define SS0B  469 // (120000+255)/256
#define OFFB  345 // ceil(1378*64/256) offset-scan blocks in off_all
#define DECB  79  // (20000+255)/256 xm1-decode blocks in off_all

typedef __attribute__((ext_vector_type(8))) short short8;
typedef __attribute__((ext_vector_type(8))) _Float16 half8;
typedef __attribute__((ext_vector_type(4))) float f32x4;

__device__ __forceinline__ float eluf(float x) {
    return x > 0.0f ? x : expm1f(x);
}

__device__ __forceinline__ unsigned f2sort(float f) {
    unsigned u = __float_as_uint(f);
    return (u & 0x80000000u) ? ~u : (u | 0x80000000u);
}
__device__ __forceinline__ float sort2f(unsigned u) {
    unsigned bits = (u & 0x80000000u) ? (u & 0x7FFFFFFFu) : ~u;
    return __uint_as_float(bits);
}
__device__ __forceinline__ unsigned short f2bf(float v) {
    unsigned u = __float_as_uint(v);
    unsigned r = (u + 0x7FFFu + ((u >> 16) & 1u)) >> 16;   // RNE
    return (unsigned short)r;
}
__device__ __forceinline__ unsigned short f2h(float v) {
    return __half_as_ushort(__float2half(v));
}
__device__ __forceinline__ float h2f(unsigned short u) {
    return __half2float(__ushort_as_half(u));
}

// ---- STAGE A: all feature-independent prep, one kernel, blockIdx ranges ----
// W2t/W3t LANE-LINEAR layout (validated +15us win): per (tap k, frag f,
// 16-col block cb) a contiguous 1KB block indexed [mc][q][8 halves].
__global__ __launch_bounds__(256) void hist_all(
    const int* __restrict__ edge1, const int* __restrict__ edge2,
    const int* __restrict__ edge3,
    const float* __restrict__ pseudo2, const float* __restrict__ pseudo3,
    const float* __restrict__ W2, const float* __restrict__ W3,
    const float* __restrict__ W1,
    const float* __restrict__ x0, const int* __restrict__ cluster0,
    int* __restrict__ blockCnt1, int* __restrict__ binTot1,
    int* __restrict__ blockCnt2, int* __restrict__ binTot2, int* __restrict__ cntD2,
    int* __restrict__ blockCnt3, int* __restrict__ binTot3, int* __restrict__ cntD3,
    unsigned short* __restrict__ W2t, unsigned short* __restrict__ W3t,
    unsigned short* __restrict__ W1t,
    unsigned* __restrict__ xm1)
{
    __shared__ float smf[64 * 129];   // 33KB; aliased as int* for hists
    int* h = (int*)smf;
    int b = blockIdx.x, t = threadIdx.x;
    if (b < HB1) {
        for (int i = t; i < 1250; i += 256) h[i] = 0;
        __syncthreads();
        for (int e = b * 256 + t; e < E1c; e += HB1 * 256)
            atomicAdd(&h[edge1[E1c + e] >> 4], 1);
        __syncthreads();
        for (int i = t; i < 1250; i += 256) {
            int v = h[i];
            blockCnt1[i * HB1 + b] = v;
            if (v) atomicAdd(&binTot1[i], v);
        }
    } else if (b < HB1 + HB2 + HB3) {
        bool is2 = b < HB1 + HB2;
        int rb = is2 ? (b - HB1) : (b - HB1 - HB2);
        int nblk = is2 ? HB2 : HB3;
        int E = is2 ? E2c : E3c;
        const int* edge = is2 ? edge2 : edge3;
        const float* pseudo = is2 ? pseudo2 : pseudo3;
        int* blockCnt = is2 ? blockCnt2 : blockCnt3;
        int* binTot = is2 ? binTot2 : binTot3;
        int* dstCnt = is2 ? cntD2 : cntD3;
        int nb = is2 ? HB2 : HB3;
        if (t < 64) h[t] = 0;
        __syncthreads();
        for (int e = rb * 256 + t; e < E; e += nblk * 256) {
            int c = 0, mul = 1;
            #pragma unroll
            for (int d = 0; d < 3; d++) {
                float p = pseudo[e * 3 + d] * 4.0f;
                float l = fminf(fmaxf(floorf(p), 0.0f), 3.0f);
                c += (int)l * mul;
                mul <<= 2;
            }
            atomicAdd(&h[c], 1);
            atomicAdd(&dstCnt[edge[E + e]], 1);
        }
        __syncthreads();
        if (t < 64) {
            int v = h[t];
            blockCnt[t * nb + rb] = v;
            if (v) atomicAdd(&binTot[t], v);
        }
    } else if (b < HB1 + HB2 + HB3 + WCVB) {
        int k = b - (HB1 + HB2 + HB3);
        for (int idx = t; idx < 4096; idx += 256) {
            int n = idx & 63, ic = idx >> 6;
            smf[ic * 65 + n] = W2[((size_t)k * 64 + ic) * 64 + n];
        }
        __syncthreads();
        for (int idx = t; idx < 4096; idx += 256) {
            int ic = idx & 63, n = idx >> 6;
            int f = ic >> 5, q = (ic >> 3) & 3, hh = ic & 7;
            int cb = n >> 4, mc = n & 15;
            W2t[((size_t)((k * 2 + f) * 4 + cb)) * 512 + mc * 32 + q * 8 + hh]
                = f2bf(smf[ic * 65 + n]);
        }
    } else if (b < HB1 + HB2 + HB3 + 2 * WCVB) {
        int k = b - (HB1 + HB2 + HB3 + WCVB);
        for (int idx = t; idx < 8192; idx += 256) {
            int n = idx & 127, ic = idx >> 7;
            smf[ic * 129 + n] = W3[((size_t)k * 64 + ic) * 128 + n];
        }
        __syncthreads();
        for (int idx = t; idx < 8192; idx += 256) {
            int ic = idx & 63, n = idx >> 6;   // n < 128
            int f = ic >> 5, q = (ic >> 3) & 3, hh = ic & 7;
            int cb = n >> 4, mc = n & 15;
            W3t[((size_t)((k * 2 + f) * 8 + cb)) * 512 + mc * 32 + q * 8 + hh]
                = f2bf(smf[ic * 129 + n]);
        }
    } else if (b < HB1 + HB2 + HB3 + 2 * WCVB + WC1B) {
        int idx = (b - (HB1 + HB2 + HB3 + 2 * WCVB)) * 256 + t;   // < 8192
        int n = idx >> 7, k = idx & 127;
        W1t[idx] = (k < 125) ? f2h(W1[k * 64 + n]) : (unsigned short)0;
    } else {
        int idx = (b - (HB1 + HB2 + HB3 + 2 * WCVB + WC1B)) * 256 + t;
        if (idx < N0c)
            atomicMax(&xm1[cluster0[idx]], f2sort(x0[idx]));
    }
}

// ---- STAGE B1: scans (conv1 1250 bins, conv2/3 bins + dsts) + chunk maps ----
__global__ __launch_bounds__(256) void plan_tot(
    const int* __restrict__ binTot1, int* __restrict__ start1,
    const int* __restrict__ binTot2, int* __restrict__ binCnt2,
    int* __restrict__ binStart2, int* __restrict__ blkPrefix2,
    int* __restrict__ chunkBin2, int* __restrict__ chunkOff2,
    const int* __restrict__ binTot3, int* __restrict__ binCnt3,
    int* __restrict__ binStart3, int* __restrict__ blkPrefix3,
    int* __restrict__ chunkBin3, int* __restrict__ chunkOff3,
    const int* __restrict__ cntD2, int* __restrict__ dstStart2,
    const int* __restrict__ cntD3, int* __restrict__ dstStart3)
{
    __shared__ int ps[256];
    __shared__ int ps64[64];
    int t = threadIdx.x;

    // conv1: thread t owns bins [5t, 5t+5)
    {
        int loc[5];
        int s = 0;
        #pragma unroll
        for (int i = 0; i < 5; i++) {
            int bin = t * 5 + i;
            int v = (bin < 1250) ? binTot1[bin] : 0;
            loc[i] = v;
            s += v;
        }
        ps[t] = s;
        __syncthreads();
        for (int ofs = 1; ofs < 256; ofs <<= 1) {
            int add = (t >= ofs) ? ps[t - ofs] : 0;
            __syncthreads();
            ps[t] += add;
            __syncthreads();
        }
        int run = (t == 0) ? 0 : ps[t - 1];
        #pragma unroll
        for (int i = 0; i < 5; i++) {
            int bin = t * 5 + i;
            if (bin < 1250) {
                start1[bin] = run;
                run += loc[i];
            }
        }
        if (t == 255) start1[1250] = run;
    }
    __syncthreads();

    // conv2: totals, starts, chunk map (chunk = 64 edges)
    if (t < 64) {
        int v = binTot2[t];
        binCnt2[t] = v;
        ps64[t] = v;
    }
    __syncthreads();
    if (t == 0) {
        int s2 = 0, p = 0;
        for (int c = 0; c < 64; c++) {
            int v = ps64[c];
            binStart2[c] = s2;
            blkPrefix2[c] = p;
            s2 += v;
            p += (v + 63) >> 6;
        }
        binStart2[64] = s2;
        blkPrefix2[64] = p;
    }
    __syncthreads();
    if (t < 64) {
        int nch = (binCnt2[t] + 63) >> 6;
        int base = blkPrefix2[t];
        for (int j = 0; j < nch; j++) {
            chunkBin2[base + j] = t;
            chunkOff2[base + j] = j;
        }
    }
    __syncthreads();

    // conv3
    if (t < 64) {
        int v = binTot3[t];
        binCnt3[t] = v;
        ps64[t] = v;
    }
    __syncthreads();
    if (t == 0) {
        int s3 = 0, p = 0;
        for (int c = 0; c < 64; c++) {
            int v = ps64[c];
            binStart3[c] = s3;
            blkPrefix3[c] = p;
            s3 += v;
            p += (v + 63) >> 6;
        }
        binStart3[64] = s3;
        blkPrefix3[64] = p;
    }
    __syncthreads();
    if (t < 64) {
        int nch = (binCnt3[t] + 63) >> 6;
        int base = blkPrefix3[t];
        for (int j = 0; j < nch; j++) {
            chunkBin3[base + j] = t;
            chunkOff3[base + j] = j;
        }
    }
    __syncthreads();

    // conv2 dst scan: 6000 bins, 24 per thread
    {
        int locd[24];
        int sd = 0;
        #pragma unroll
        for (int i = 0; i < 24; i++) {
            int bin = t * 24 + i;
            int vv = (bin < N2c) ? cntD2[bin] : 0;
            locd[i] = vv;
            sd += vv;
        }
        ps[t] = sd;
        __syncthreads();
        for (int ofs = 1; ofs < 256; ofs <<= 1) {
            int add = (t >= ofs) ? ps[t - ofs] : 0;
            __syncthreads();
            ps[t] += add;
            __syncthreads();
        }
        int rund = (t == 0) ? 0 : ps[t - 1];
        #pragma unroll
        for (int i = 0; i < 24; i++) {
            int bin = t * 24 + i;
            if (bin < N2c) { dstStart2[bin] = rund; rund += locd[i]; }
        }
        if (t == 255) dstStart2[N2c] = ps[255];
    }
    __syncthreads();

    // conv3 dst scan: 1600 bins, 7 per thread
    {
        int locd[7];
        int sd = 0;
        #pragma unroll
        for (int i = 0; i < 7; i++) {
            int bin = t * 7 + i;
            int vv = (bin < N3c) ? cntD3[bin] : 0;
            locd[i] = vv;
            sd += vv;
        }
        ps[t] = sd;
        __syncthreads();
        for (int ofs = 1; ofs < 256; ofs <<= 1) {
            int add = (t >= ofs) ? ps[t - ofs] : 0;
            __syncthreads();
            ps[t] += add;
            __syncthreads();
        }
        int rund = (t == 0) ? 0 : ps[t - 1];
        #pragma unroll
        for (int i = 0; i < 7; i++) {
            int bin = t * 7 + i;
            if (bin < N3c) { dstStart3[bin] = rund; rund += locd[i]; }
        }
        if (t == 255) dstStart3[N3c] = ps[255];
    }
}

// ---- STAGE B2: per-(bin,block) offsets (one wave per bin-row, shfl scan)
// + xm1 sortable->fp32 decode (runs before scatter reads fp32 x).
__global__ __launch_bounds__(256) void off_all(
    const int* __restrict__ blockCnt1, const int* __restrict__ start1,
    int* __restrict__ blockOff1,
    const int* __restrict__ blockCnt2, const int* __restrict__ binStart2,
    int* __restrict__ blockOff2,
    const int* __restrict__ blockCnt3, const int* __restrict__ binStart3,
    int* __restrict__ blockOff3,
    unsigned* __restrict__ xm1)
{
    if (blockIdx.x >= OFFB) {
        int idx = (blockIdx.x - OFFB) * 256 + threadIdx.x;
        if (idx < N1c) {
            float f = sort2f(xm1[idx]);
            unsigned bb = __float_as_uint(f);
            if ((bb & 0x7F800000u) == 0x7F800000u) f = 0.0f;
            ((float*)xm1)[idx] = f;
        }
        return;
    }
    int wid = (blockIdx.x * 256 + threadIdx.x) >> 6;
    int lane = threadIdx.x & 63;
    if (wid >= 1250 + 64 + 64) return;
    const int* c;
    int* o;
    int run, width;
    if (wid < 1250) {
        c = blockCnt1 + (size_t)wid * HB1;
        o = blockOff1 + (size_t)wid * HB1;
        run = start1[wid];
        width = HB1;
    } else if (wid < 1250 + 64) {
        int bin = wid - 1250;
        c = blockCnt2 + (size_t)bin * HB2;
        o = blockOff2 + (size_t)bin * HB2;
        run = binStart2[bin];
        width = HB2;
    } else {
        int bin = wid - 1314;
        c = blockCnt3 + (size_t)bin * HB3;
        o = blockOff3 + (size_t)bin * HB3;
        run = binStart3[bin];
        width = HB3;
    }
    for (int base = 0; base < width; base += 64) {
        int b = base + lane;
        int v = (b < width) ? c[b] : 0;
        int inc = v;
        #pragma unroll
        for (int ofs = 1; ofs < 64; ofs <<= 1) {
            int u = __shfl_up(inc, ofs);
            if (lane >= ofs) inc += u;
        }
        if (b < width) o[b] = run + inc - v;
        run += __shfl(inc, 63);
    }
}

// ---- STAGE C: scatter EDGE RECORDS ----
// conv1: 1250-bin placement; xv INLINED into the record:
//        rec1 = { f0:fp16<<16 | kbase<<4 | ln, xv:f32, f1:f32, f2:f32 }.
// conv2/3: cube-bin placement + dst-sorted posList (counting sort).
__global__ __launch_bounds__(256) void scatter_all(
    const int* __restrict__ edge1, const float* __restrict__ pseudo1,
    const int* __restrict__ edge2, const float* __restrict__ pseudo2,
    const int* __restrict__ edge3, const float* __restrict__ pseudo3,
    const int* __restrict__ blockOff1,
    const int* __restrict__ blockOff2, const int* __restrict__ blockOff3,
    int4* __restrict__ rec1, int4* __restrict__ rec2, int4* __restrict__ rec3,
    const float* __restrict__ x1,
    const int* __restrict__ dstStart2, const int* __restrict__ dstStart3,
    int* __restrict__ curD2, int* __restrict__ curD3,
    int* __restrict__ posList2, int* __restrict__ posList3)
{
    __shared__ int cur[1250];
    int b = blockIdx.x, t = threadIdx.x;
    if (b < HB1) {
        for (int i = t; i < 1250; i += 256) cur[i] = blockOff1[(size_t)i * HB1 + b];
        __syncthreads();
        for (int e = b * 256 + t; e < E1c; e += HB1 * 256) {
            int src = edge1[e], dst = edge1[E1c + e];
            float f[3];
            int kbase = 0, mul5 = 1;
            #pragma unroll
            for (int d = 0; d < 3; d++) {
                float pp = pseudo1[e * 3 + d] * 4.0f;
                float l = fminf(fmaxf(floorf(pp), 0.0f), 3.0f);
                f[d] = pp - l;
                kbase += (int)l * mul5;
                mul5 *= 5;
            }
            float xv = x1[src];
            int p = atomicAdd(&cur[dst >> 4], 1);
            rec1[p] = make_int4(((int)f2h(f[0]) << 16) | (kbase << 4) | (dst & 15),
                                __float_as_int(xv), __float_as_int(f[1]),
                                __float_as_int(f[2]));
        }
    } else {
        bool is2 = b < HB1 + HB2;
        int rb = is2 ? (b - HB1) : (b - HB1 - HB2);
        int nblk = is2 ? HB2 : HB3;
        int E = is2 ? E2c : E3c;
        const int* edge = is2 ? edge2 : edge3;
        const float* pseudo = is2 ? pseudo2 : pseudo3;
        const int* blockOff = is2 ? blockOff2 : blockOff3;
        int4* rec = is2 ? rec2 : rec3;
        const int* dstStart = is2 ? dstStart2 : dstStart3;
        int* curD = is2 ? curD2 : curD3;
        int* posList = is2 ? posList2 : posList3;
        int nb = is2 ? HB2 : HB3;
        if (t < 64) cur[t] = blockOff[(size_t)t * nb + rb];
        __syncthreads();
        for (int e = rb * 256 + t; e < E; e += nblk * 256) {
            int src = edge[e], dst = edge[E + e];
            float f[3];
            int c = 0, mul = 1;
            #pragma unroll
            for (int d = 0; d < 3; d++) {
                float pp = pseudo[e * 3 + d] * 4.0f;
                float l = fminf(fmaxf(floorf(pp), 0.0f), 3.0f);
                f[d] = pp - l;
                c += (int)l * mul;
                mul <<= 2;
            }
            int p = atomicAdd(&cur[c], 1);
            rec[p] = make_int4(src | (dst << 16),
                               __float_as_int(f[0]), __float_as_int(f[1]),
                               __float_as_int(f[2]));
            int qd = dstStart[dst] + atomicAdd(&curD[dst], 1);
            posList[qd] = p;
        }
    }
}

// ---- conv1 (C_in=1): per-16-node block, LDS knot accumulation; epilogue is
// a 16x64x128 fp16 MFMA GEMM (T16 @ W1t). Pools into xm2 via atomicMax.
__global__ __launch_bounds__(256) void conv1_block(
    const int4* __restrict__ rec, const float* __restrict__ x,
    const int* __restrict__ start,
    const unsigned short* __restrict__ W1t,   // [64][128] fp16 k-contig
    const float* __restrict__ root,
    const float* __restrict__ bias, const int* __restrict__ cl,
    unsigned* __restrict__ xmOut) {
    __shared__ float T[16][128];
    __shared__ unsigned short T16[16][136];   // pad 136: 16B-aligned rows, 2-way banks
    __shared__ int degL[16];
    int b = blockIdx.x;
    int t = threadIdx.x;
    for (int j = t; j < 2048; j += 256) ((float*)T)[j] = 0.0f;
    if (t < 16) degL[t] = 0;
    __syncthreads();
    int s0 = start[b], s1 = start[b + 1];
    for (int i = s0 + t; i < s1; i += 256) {
        int4 r = rec[i];
        int ln = r.x & 15;
        int kbase = (r.x >> 4) & 127;
        float f0 = h2f((unsigned short)((unsigned)r.x >> 16));
        float xv = __int_as_float(r.y);
        float f1 = __int_as_float(r.z);
        float f2 = __int_as_float(r.w);
        #pragma unroll
        for (int s = 0; s < 8; s++) {
            int b0 = s & 1, b1 = (s >> 1) & 1, b2 = (s >> 2) & 1;
            float w0 = b0 ? f0 : 1.0f - f0;
            float w1 = b1 ? f1 : 1.0f - f1;
            float w2 = b2 ? f2 : 1.0f - f2;
            int k = kbase + b0 + 5 * b1 + 25 * b2;
            atomicAdd(&T[ln][k], xv * w0 * w1 * w2);
        }
        atomicAdd(&degL[ln], 1);
    }
    __syncthreads();
    // T fp32 -> T16 fp16 (k 125..127 are zero from init)
    for (int j = t; j < 2048; j += 256) {
        int node = j >> 7, k = j & 127;
        T16[node][k] = f2h(T[node][k]);
    }
    __syncthreads();
    int w = t >> 6, lane = t & 63;
    int q = lane >> 4, mcol = lane & 15;
    const unsigned short* ar = &T16[mcol][0];
    half8 a0 = *(const half8*)(ar + q * 8);
    half8 a1 = *(const half8*)(ar + 32 + q * 8);
    half8 a2 = *(const half8*)(ar + 64 + q * 8);
    half8 a3 = *(const half8*)(ar + 96 + q * 8);
    int ch = w * 16 + mcol;
    const unsigned short* br = W1t + (size_t)ch * 128;
    half8 b0 = *(const half8*)(br + q * 8);
    half8 b1 = *(const half8*)(br + 32 + q * 8);
    half8 b2 = *(const half8*)(br + 64 + q * 8);
    half8 b3 = *(const half8*)(br + 96 + q * 8);
    f32x4 c = (f32x4){0.0f, 0.0f, 0.0f, 0.0f};
    c = __builtin_amdgcn_mfma_f32_16x16x32_f16(a0, b0, c, 0, 0, 0);
    c = __builtin_amdgcn_mfma_f32_16x16x32_f16(a1, b1, c, 0, 0, 0);
    c = __builtin_amdgcn_mfma_f32_16x16x32_f16(a2, b2, c, 0, 0, 0);
    c = __builtin_amdgcn_mfma_f32_16x16x32_f16(a3, b3, c, 0, 0, 0);
    int v0 = b << 4;
    float rt_ = root[ch], bi = bias[ch];
    #pragma unroll
    for (int r = 0; r < 4; r++) {
        int node = q * 4 + r;
        int v = v0 + node;
        float d = fmaxf((float)degL[node], 1.0f);
        float val = eluf(c[r] / d + x[v] * rt_ + bi);
        atomicMax(&xmOut[((size_t)cl[v] << 6) + ch], f2sort(val));
    }
}

// decode pooled sortable-uint buffer -> fp32 (in place) + bf16 copy
__global__ void decode_cvt(unsigned* __restrict__ buf,
                           unsigned short* __restrict__ xb, int total) {
    int idx = blockIdx.x * blockDim.x + threadIdx.x;
    if (idx >= total) return;
    float f = sort2f(buf[idx]);
    unsigned b = __float_as_uint(f);
    if ((b & 0x7F800000u) == 0x7F800000u) f = 0.0f;
    ((float*)buf)[idx] = f;
    xb[idx] = f2bf(f);
}

// Binned spline-conv via bf16 MFMA. Wave = 64 edges x 32 cols (2 N-tiles),
// gridDim.y = COUT/32 column slices. B-fragments read from LANE-LINEAR Wt
// layout: each load = contiguous 1KB (ideal coalescing; the old 128B-stride
// pattern touched 16 scattered lines per inst -> TA serialization was the
// work-invariant global bottleneck). B double-buffered across taps.
template<int COUT>
__global__ __launch_bounds__(256) void spline_mfma(
    const int4* __restrict__ recs,
    const unsigned short* __restrict__ Wt,
    const unsigned short* __restrict__ xb,
    const int* __restrict__ binStart,
    const int* __restrict__ binCnt,
    const int* __restrict__ blkPrefix,
    const int* __restrict__ chunkBin,
    const int* __restrict__ chunkOff,
    unsigned short* __restrict__ msg)
{
    __shared__ float basisS[4][8][64];
    __shared__ int srcS[4][64];

    int w = threadIdx.x >> 6, lane = threadIdx.x & 63;
    int c = blockIdx.x * 4 + w;
    if (c >= blkPrefix[64]) return;
    int bin = chunkBin[c];
    int chunk = chunkOff[c];
    int cnt = binCnt[bin];

    {
        int pos = chunk * 64 + lane;
        bool act = pos < cnt;
        int4 r = act ? recs[binStart[bin] + pos] : make_int4(0, 0, 0, 0);
        srcS[w][lane] = r.x & 0xFFFF;
        float f0 = __int_as_float(r.y);
        float f1 = __int_as_float(r.z);
        float f2 = __int_as_float(r.w);
        #pragma unroll
        for (int s = 0; s < 8; s++) {
            float w0 = (s & 1) ? f0 : 1.0f - f0;
            float w1 = (s & 2) ? f1 : 1.0f - f1;
            float w2 = (s & 4) ? f2 : 1.0f - f2;
            basisS[w][s][lane] = act ? (w0 * w1 * w2) : 0.0f;
        }
    }
    __builtin_amdgcn_wave_barrier();
    __threadfence_block();

    int lo0 = bin & 3, lo1 = (bin >> 2) & 3, lo2 = bin >> 4;
    int kbase = lo0 + 5 * lo1 + 25 * lo2;
    int colOff = blockIdx.y << 5;   // 32-col slice
    int q = lane >> 4;        // quad
    int mcol = lane & 15;
    int cb0 = colOff >> 4;
    int lof = (mcol << 5) + (q << 3);   // lane offset in halves within 512-half block

    short8 afr[4][2];
    #pragma unroll
    for (int rt = 0; rt < 4; rt++) {
        int src = srcS[w][rt * 16 + mcol];
        const unsigned short* xr = xb + ((size_t)src << 6) + q * 8;
        afr[rt][0] = *(const short8*)(xr);
        afr[rt][1] = *(const short8*)(xr + 32);
    }

    f32x4 acc[4][2];
    #pragma unroll
    for (int rt = 0; rt < 4; rt++)
        #pragma unroll
        for (int nt = 0; nt < 2; nt++)
            acc[rt][nt] = (f32x4){0.0f, 0.0f, 0.0f, 0.0f};
    const f32x4 zero4 = {0.0f, 0.0f, 0.0f, 0.0f};

    // tap-k: k(s) = kbase + (s&1) + 5*((s>>1)&1) + 25*(s>>2)
    short8 bcur[2][2];
    {
        #pragma unroll
        for (int nt = 0; nt < 2; nt++) {
            bcur[nt][0] = *(const short8*)(Wt + ((size_t)((kbase * 2 + 0) * (COUT >> 4) + cb0 + nt)) * 512 + lof);
            bcur[nt][1] = *(const short8*)(Wt + ((size_t)((kbase * 2 + 1) * (COUT >> 4) + cb0 + nt)) * 512 + lof);
        }
    }
    #pragma unroll 1
    for (int s = 0; s < 8; s++) {
        short8 bnx[2][2];
        if (s < 7) {
            int sn = s + 1;
            int kn = kbase + (sn & 1) + 5 * ((sn >> 1) & 1) + 25 * (sn >> 2);
            #pragma unroll
            for (int nt = 0; nt < 2; nt++) {
                bnx[nt][0] = *(const short8*)(Wt + ((size_t)((kn * 2 + 0) * (COUT >> 4) + cb0 + nt)) * 512 + lof);
                bnx[nt][1] = *(const short8*)(Wt + ((size_t)((kn * 2 + 1) * (COUT >> 4) + cb0 + nt)) * 512 + lof);
            }
        }
        #pragma unroll
        for (int rt = 0; rt < 4; rt++) {
            f32x4 ct[2];
            #pragma unroll
            for (int nt = 0; nt < 2; nt++) {
                ct[nt] = __builtin_amdgcn_mfma_f32_16x16x32_bf16(afr[rt][0], bcur[nt][0], zero4, 0, 0, 0);
                ct[nt] = __builtin_amdgcn_mfma_f32_16x16x32_bf16(afr[rt][1], bcur[nt][1], ct[nt], 0, 0, 0);
            }
            #pragma unroll
            for (int r = 0; r < 4; r++) {
                float bs = basisS[w][s][rt * 16 + q * 4 + r];
                #pragma unroll
                for (int nt = 0; nt < 2; nt++)
                    acc[rt][nt][r] = fmaf(bs, ct[nt][r], acc[rt][nt][r]);
            }
        }
        if (s < 7) {
            #pragma unroll
            for (int nt = 0; nt < 2; nt++) {
                bcur[nt][0] = bnx[nt][0];
                bcur[nt][1] = bnx[nt][1];
            }
        }
    }

    // Epilogue: streaming fp16 stores in record order (C row = q*4+r).
    int base = binStart[bin] + chunk * 64;
    #pragma unroll
    for (int rt = 0; rt < 4; rt++) {
        #pragma unroll
        for (int r = 0; r < 4; r++) {
            int row = rt * 16 + q * 4 + r;
            if (chunk * 64 + row < cnt) {
                unsigned short* mp = msg + (size_t)(base + row) * COUT + colOff + mcol;
                mp[0]  = f2h(acc[rt][0][r]);
                mp[16] = f2h(acc[rt][1][r]);
            }
        }
    }
}

// gather-aggregate + node update (mean + root matmul + bias + elu) + pool,
// COUT=64. One wave per node; posList gives dst-sorted msg rows.
__global__ __launch_bounds__(256) void agg_update64(
    const unsigned short* __restrict__ msg, const int* __restrict__ posList,
    const int* __restrict__ dstStart,
    const float* __restrict__ xm, const float* __restrict__ root,
    const float* __restrict__ bias, const int* __restrict__ cl,
    unsigned* __restrict__ xmOut, int nNodes) {
    __shared__ float xsh[4][64];
    int w = threadIdx.x >> 6, lane = threadIdx.x & 63;
    int v = blockIdx.x * 4 + w;
    if (v >= nNodes) return;
    xsh[w][lane] = xm[((size_t)v << 6) + lane];
    int s0 = dstStart[v], s1 = dstStart[v + 1];
    float a0 = 0.0f, a1 = 0.0f, a2 = 0.0f, a3 = 0.0f;
    int i = s0;
    for (; i + 4 <= s1; i += 4) {
        int p0 = posList[i], p1 = posList[i + 1];
        int p2 = posList[i + 2], p3 = posList[i + 3];
        a0 += h2f(msg[((size_t)p0 << 6) + lane]);
        a1 += h2f(msg[((size_t)p1 << 6) + lane]);
        a2 += h2f(msg[((size_t)p2 << 6) + lane]);
        a3 += h2f(msg[((size_t)p3 << 6) + lane]);
    }
    for (; i < s1; i++)
        a0 += h2f(msg[((size_t)posList[i] << 6) + lane]);
    float a = (a0 + a1 + a2 + a3) / fmaxf((float)(s1 - s0), 1.0f);
    float r = 0.0f;
    #pragma unroll 8
    for (int j = 0; j < 64; j++)
        r = fmaf(xsh[w][j], root[(j << 6) + lane], r);
    float val = eluf(a + r + bias[lane]);
    atomicMax(&xmOut[((size_t)cl[v] << 6) + lane], f2sort(val));
}

// gather-aggregate + node update + pool, COUT=128 (2 channels/lane).
__global__ __launch_bounds__(256) void agg_update128(
    const unsigned short* __restrict__ msg, const int* __restrict__ posList,
    const int* __restrict__ dstStart,
    const float* __restrict__ xm, const float* __restrict__ root,
    const float* __restrict__ bias, const int* __restrict__ cl,
    unsigned* __restrict__ xmOut, int nNodes) {
    __shared__ float xsh[4][64];
    int w = threadIdx.x >> 6, lane = threadIdx.x & 63;
    int v = blockIdx.x * 4 + w;
    if (v >= nNodes) return;
    xsh[w][lane] = xm[((size_t)v << 6) + lane];
    int s0 = dstStart[v], s1 = dstStart[v + 1];
    float c0a = 0.0f, c0b = 0.0f, c1a = 0.0f, c1b = 0.0f;
    int i = s0;
    for (; i + 2 <= s1; i += 2) {
        int p0 = posList[i], p1 = posList[i + 1];
        const unsigned short* m0 = msg + ((size_t)p0 << 7);
        const unsigned short* m1 = msg + ((size_t)p1 << 7);
        c0a += h2f(m0[lane]); c0b += h2f(m0[64 + lane]);
        c1a += h2f(m1[lane]); c1b += h2f(m1[64 + lane]);
    }
    for (; i < s1; i++) {
        const unsigned short* m0 = msg + ((size_t)posList[i] << 7);
        c0a += h2f(m0[lane]); c0b += h2f(m0[64 + lane]);
    }
    float dinv = 1.0f / fmaxf((float)(s1 - s0), 1.0f);
    float aa0 = (c0a + c1a) * dinv;
    float aa1 = (c0b + c1b) * dinv;
    float r0 = 0.0f, r1 = 0.0f;
    #pragma unroll 8
    for (int j = 0; j < 64; j++) {
        float xi = xsh[w][j];
        r0 = fmaf(xi, root[(j << 7) + lane], r0);
        r1 = fmaf(xi, root[(j << 7) + 64 + lane], r1);
    }
    unsigned* orow = xmOut + ((size_t)cl[v] << 7);
    atomicMax(&orow[lane], f2sort(eluf(aa0 + r0 + bias[lane])));
    atomicMax(&orow[64 + lane], f2sort(eluf(aa1 + r1 + bias[lane + 64])));
}

// fc1 k-split: grid (64 rows, 8 k-slices). Inline sortable-uint decode of xm4.
__global__ __launch_bounds__(256) void fc1_split(
    const unsigned* __restrict__ xin, const float* __restrict__ w1,
    float* __restrict__ h) {
    __shared__ float xsh[128];
    int row = blockIdx.x, ks = blockIdx.y;
    int o = threadIdx.x;
    if (o < 128) {
        float f = sort2f(xin[row * 1024 + ks * 128 + o]);
        unsigned bb = __float_as_uint(f);
        if ((bb & 0x7F800000u) == 0x7F800000u) f = 0.0f;
        xsh[o] = f;
    }
    __syncthreads();
    float acc = 0.0f;
    const float* wp = w1 + (size_t)ks * 128 * 256 + o;
    #pragma unroll 8
    for (int i = 0; i < 128; i++)
        acc = fmaf(xsh[i], wp[i * 256], acc);
    atomicAdd(&h[row * 256 + o], acc);
}

// fc2 + log_softmax: elu(h+b1) @ w2 + b2. One block (64 thr) per row.
__global__ __launch_bounds__(64) void fc2_k(
    const float* __restrict__ h, const float* __restrict__ b1,
    const float* __restrict__ w2, const float* __restrict__ b2,
    float* __restrict__ out) {
    __shared__ float hs[256];
    __shared__ float lg[10];
    int row = blockIdx.x;
    int t = threadIdx.x;
    for (int i = t; i < 256; i += 64) hs[i] = eluf(h[row * 256 + i] + b1[i]);
    __syncthreads();
    if (t < 10) {
        float a = b2[t];
        for (int i = 0; i < 256; i++) a = fmaf(hs[i], w2[i * 10 + t], a);
        lg[t] = a;
    }
    __syncthreads();
    if (t < 10) {
        float m = -1e30f;
        #pragma unroll
        for (int j = 0; j < 10; j++) m = fmaxf(m, lg[j]);
        float sum = 0.0f;
        #pragma unroll
        for (int j = 0; j < 10; j++) sum += expf(lg[j] - m);
        out[row * 10 + t] = lg[t] - m - logf(sum);
    }
}

extern "C" void kernel_launch(void* const* d_in, const int* in_sizes, int n_in,
                              void* d_out, int out_size, void* d_ws, size_t ws_size,
                              hipStream_t stream) {
    const float* x0      = (const float*)d_in[0];
    const int*   cluster0= (const int*)d_in[1];
    const int*   edge1   = (const int*)d_in[2];
    const float* pseudo1 = (const float*)d_in[3];
    const float* W1      = (const float*)d_in[4];
    const float* root1   = (const float*)d_in[5];
    const float* b1      = (const float*)d_in[6];
    const int*   cluster1= (const int*)d_in[7];
    const int*   edge2   = (const int*)d_in[8];
    const float* pseudo2 = (const float*)d_in[9];
    const float* W2      = (const float*)d_in[10];
    const float* root2   = (const float*)d_in[11];
    const float* b2      = (const float*)d_in[12];
    const int*   cluster2= (const int*)d_in[13];
    const int*   edge3   = (const int*)d_in[14];
    const float* pseudo3 = (const float*)d_in[15];
    const float* W3      = (const float*)d_in[16];
    const float* root3   = (const float*)d_in[17];
    const float* b3      = (const float*)d_in[18];
    const int*   cluster3= (const int*)d_in[19];
    const float* fc1_w   = (const float*)d_in[20];
    const float* fc1_b   = (const float*)d_in[21];
    const float* fc2_w   = (const float*)d_in[22];
    const float* fc2_b   = (const float*)d_in[23];
    float* out = (float*)d_out;

    float* ws = (float*)d_ws;
    size_t off = 0;
    // ---- zeroed region ----
    float* xm1  = ws + off; off += 20480;
    float* xm2  = ws + off; off += (size_t)N2c * 64;
    float* xm3  = ws + off; off += (size_t)N3c * 64;
    float* xm4  = ws + off; off += 512 * 128;
    float* h1   = ws + off; off += 64 * 256;
    int* cntD2   = (int*)(ws + off); off += 6016;
    int* cntD3   = (int*)(ws + off); off += 1664;
    int* curD2   = (int*)(ws + off); off += 6016;
    int* curD3   = (int*)(ws + off); off += 1664;
    int* binTot1 = (int*)(ws + off); off += 1280;
    int* binTot2 = (int*)(ws + off); off += 64;
    int* binTot3 = (int*)(ws + off); off += 64;
    size_t zeroFloats = off;
    // ---- non-zeroed region (fully written before read every launch) ----
    int4* rec1 = (int4*)(ws + off); off += (size_t)E1c * 4;
    int4* rec2 = (int4*)(ws + off); off += (size_t)E2c * 4;
    int4* rec3 = (int4*)(ws + off); off += (size_t)E3c * 4;
    unsigned short* W2t = (unsigned short*)(ws + off); off += 256000;
    unsigned short* W3t = (unsigned short*)(ws + off); off += 512000;
    unsigned short* W1t = (unsigned short*)(ws + off); off += 4096;
    unsigned short* xb2 = (unsigned short*)(ws + off); off += 192000;
    unsigned short* xb3 = (unsigned short*)(ws + off); off += 51200;
    int* start1    = (int*)(ws + off); off += 1280;
    int* blockCnt1 = (int*)(ws + off); off += (size_t)HB1 * 1250;
    int* blockOff1 = (int*)(ws + off); off += (size_t)HB1 * 1250;
    int* blockCnt2 = (int*)(ws + off); off += (size_t)HB2 * 64;
    int* blockOff2 = (int*)(ws + off); off += (size_t)HB2 * 64;
    int* blockCnt3 = (int*)(ws + off); off += (size_t)HB3 * 64;
    int* blockOff3 = (int*)(ws + off); off += (size_t)HB3 * 64;
    int* binCnt2   = (int*)(ws + off); off += 64;
    int* binStart2 = (int*)(ws + off); off += 80;
    int* blkPrefix2= (int*)(ws + off); off += 80;
    int* chunkBin2 = (int*)(ws + off); off += 2560;
    int* chunkOff2 = (int*)(ws + off); off += 2560;
    int* binCnt3   = (int*)(ws + off); off += 64;
    int* binStart3 = (int*)(ws + off); off += 80;
    int* blkPrefix3= (int*)(ws + off); off += 80;
    int* chunkBin3 = (int*)(ws + off); off += 768;
    int* chunkOff3 = (int*)(ws + off); off += 768;
    int* dstStart2 = (int*)(ws + off); off += 6016;
    int* dstStart3 = (int*)(ws + off); off += 1664;
    int* posList2  = (int*)(ws + off); off += E2c;
    int* posList3  = (int*)(ws + off); off += E3c;
    // shared fp16 message buffer: conv2 E2*64 halves, conv3 E3*128 (smaller)
    unsigned short* msg = (unsigned short*)(ws + off); off += (size_t)E2c * 32;

    hipMemsetAsync(d_ws, 0, zeroFloats * sizeof(float), stream);

    // A: hists + W transpose-cvt (lane-linear W2t/W3t, W1 fp16) + pool0
    hist_all<<<HB1 + HB2 + HB3 + 2 * WCVB + WC1B + SS0B, 256, 0, stream>>>(
        edge1, edge2, edge3, pseudo2, pseudo3, W2, W3, W1, x0, cluster0,
        blockCnt1, binTot1, blockCnt2, binTot2, cntD2,
        blockCnt3, binTot3, cntD3, W2t, W3t, W1t, (unsigned*)xm1);

    // B1: scans (conv1 bins, conv2/3 bins + dsts) + chunk maps
    plan_tot<<<1, 256, 0, stream>>>(
        binTot1, start1,
        binTot2, binCnt2, binStart2, blkPrefix2, chunkBin2, chunkOff2,
        binTot3, binCnt3, binStart3, blkPrefix3, chunkBin3, chunkOff3,
        cntD2, dstStart2, cntD3, dstStart3);

    // B2: per-(bin,block) offsets (wave scan) + xm1 decode
    off_all<<<OFFB + DECB, 256, 0, stream>>>(
        blockCnt1, start1, blockOff1,
        blockCnt2, binStart2, blockOff2,
        blockCnt3, binStart3, blockOff3, (unsigned*)xm1);

    // C: scatter edge records (conv1 with inlined xv) + posLists
    scatter_all<<<HB1 + HB2 + HB3, 256, 0, stream>>>(
        edge1, pseudo1, edge2, pseudo2, edge3, pseudo3,
        blockOff1, blockOff2, blockOff3, rec1, rec2, rec3, xm1,
        dstStart2, dstStart3, curD2, curD3, posList2, posList3);

    // conv1 (1->64): LDS knot accumulation + fp16 MFMA epilogue + pool
    conv1_block<<<1250, 256, 0, stream>>>(rec1, xm1, start1, W1t, root1, b1,
                                          cluster1, (unsigned*)xm2);
    decode_cvt<<<(N2c * 64) / 256, 256, 0, stream>>>((unsigned*)xm2, xb2, N2c * 64);

    // conv2 (64->64): coalesced-B MFMA -> fp16 msg, gather-agg + pool
    spline_mfma<64><<<dim3((E2c / 64 + 64 + 3) / 4, 2), 256, 0, stream>>>(
        rec2, W2t, xb2, binStart2, binCnt2, blkPrefix2, chunkBin2, chunkOff2, msg);
    agg_update64<<<(N2c + 3) / 4, 256, 0, stream>>>(msg, posList2, dstStart2,
                                                    xm2, root2, b2, cluster2,
                                                    (unsigned*)xm3, N2c);
    decode_cvt<<<(N3c * 64) / 256, 256, 0, stream>>>((unsigned*)xm3, xb3, N3c * 64);

    // conv3 (64->128): coalesced-B MFMA -> fp16 msg, gather-agg + pool
    spline_mfma<128><<<dim3((E3c / 64 + 64 + 3) / 4, 4), 256, 0, stream>>>(
        rec3, W3t, xb3, binStart3, binCnt3, blkPrefix3, chunkBin3, chunkOff3, msg);
    agg_update128<<<(N3c + 3) / 4, 256, 0, stream>>>(msg, posList3, dstStart3,
                                                     xm3, root3, b3, cluster3,
                                                     (unsigned*)xm4, N3c);

    // FC head: k-split fc1 (inline xm4 decode) + fused fc2/log_softmax
    fc1_split<<<dim3(64, 8), 256, 0, stream>>>((unsigned*)xm4, fc1_w, h1);
    fc2_k<<<64, 64, 0, stream>>>(h1, fc1_b, fc2_w, fc2_b, out);
}